// Round 11
// baseline (323.870 us; speedup 1.0000x reference)
//
#include <hip/hip_runtime.h>

typedef unsigned short u16;
typedef unsigned int u32;
typedef __attribute__((ext_vector_type(8))) short short8;
typedef __attribute__((ext_vector_type(4))) float floatx4;

typedef const u32 __attribute__((address_space(1))) glb_u32;
typedef u32 __attribute__((address_space(3))) lds_u32;

__device__ inline float bf2f(u16 h) {
  union { u32 u; float f; } v; v.u = ((u32)h) << 16; return v.f;
}
__device__ inline u16 f2bf(float f) {
  union { float f; u32 u; } v; v.f = f;
  u32 u = v.u;
  return (u16)((u + 0x7fffu + ((u >> 16) & 1u)) >> 16);
}
// dtype-generic load: isbf is wave-uniform (from per-block sniffer)
__device__ inline float ldf(const void* p, int i, int isbf) {
  return isbf ? bf2f(((const u16*)p)[i]) : ((const float*)p)[i];
}
// async global->LDS DMA: 16B/lane, dest = wave-uniform base + lane*16, src per-lane
__device__ inline void gl16(const void* g, void* l) {
  __builtin_amdgcn_global_load_lds((glb_u32*)g, (lds_u32*)l, 16, 0, 0);
}

// ---------------- K1: fused prep (R9 verified) ----------------
// One kernel, 1614 blocks, three roles (block-uniform branch):
//   [0,78)      styles rows  -> s[8][512], cw[35][512], cb[35][512]
//   [78,590)    wprep        -> wT[ck][ctblk][(tap*4+q)*64+co] cells, wsqT2[co][ci]
//   [590,1614)  xtrans       -> xT[b][ck][h][q][w] bf16 cells; block per (b,ck,h8)
__global__ __launch_bounds__(256) void prep_kernel(
    const void* __restrict__ style, const void* __restrict__ class_style,
    const void* __restrict__ weight,
    const void* __restrict__ mod_w, const void* __restrict__ mod_b,
    const void* __restrict__ cw_w, const void* __restrict__ cw_b,
    const void* __restrict__ cb_w, const void* __restrict__ cb_b,
    const void* __restrict__ x,
    float* __restrict__ s, float* __restrict__ cw, float* __restrict__ cb,
    u16* __restrict__ wT, float* __restrict__ wsqT2, u16* __restrict__ xT) {
  __shared__ float smem[4608];       // union: styles v[512] | wprep wsmem[4608] | xtrans sv[512]+pr[256]+sl[32]
  __shared__ int cnt;
  const int t = threadIdx.x;

  if (t == 0) cnt = 0;
  __syncthreads();
  {
    u32 v = ((const u32*)weight)[1024 + t];
    int e = (v >> 7) & 0xFF;
    if (e >= 96 && e <= 160) atomicAdd(&cnt, 1);
  }
  __syncthreads();
  const int isbf = (cnt >= 154) ? 1 : 0;
  const int bid = blockIdx.x;

  if (bid < 78) {
    // ---- styles role ----
    int row = bid;
    const void *vec, *wm, *bias; float* out; int voff;
    if (row < 8)        { vec = style;       voff = row*512;      wm = mod_w; bias = mod_b; out = s  + row*512; }
    else if (row < 43)  { vec = class_style; voff = (row-8)*512;  wm = cw_w;  bias = cw_b;  out = cw + (row-8)*512; }
    else                { vec = class_style; voff = (row-43)*512; wm = cb_w;  bias = cb_b;  out = cb + (row-43)*512; }
    float* v = smem;
    for (int i = t; i < 512; i += 256) v[i] = ldf(vec, voff + i, isbf);
    __syncthreads();
    const float inv = 0.04419417382415922f;  // 1/sqrt(512)
    for (int o = t; o < 512; o += 256) {
      float acc = 0.f;
      if (isbf) {
        for (int k = 0; k < 512; ++k) acc += bf2f(((const u16*)wm)[o*512 + k]) * v[k];
      } else {
        const float4* wr = (const float4*)((const float*)wm + o*512);
        for (int k = 0; k < 128; ++k) {
          float4 p = wr[k];
          acc += p.x*v[k*4+0] + p.y*v[k*4+1] + p.z*v[k*4+2] + p.w*v[k*4+3];
        }
      }
      out[o] = acc * inv + ldf(bias, o, isbf);
    }
  } else if (bid < 590) {
    // ---- wprep role ----
    const int co = bid - 78;
    const int ctb = co >> 6, col = co & 63;
    float* wsmem = smem;
    for (int i = t; i < 4608; i += 256)
      wsmem[i] = ldf(weight, co*4608 + i, isbf);   // coalesced
    __syncthreads();
    for (int ci = t; ci < 512; ci += 256) {
      float sq = 0.f;
      const int ck = ci >> 5, q = (ci >> 3) & 3, e = ci & 7;
      #pragma unroll
      for (int tap = 0; tap < 9; ++tap) {
        float fv = wsmem[ci*9 + tap];
        sq += fv*fv;
        wT[((size_t)(ck*8 + ctb)*2304 + (tap*4 + q)*64 + col)*8 + e] = f2bf(fv);
      }
      wsqT2[(size_t)co*512 + ci] = sq;             // coalesced store
    }
  } else {
    // ---- xtrans role: block per (b, ck, h8); s once per 8 h rows ----
    const int r = bid - 590;
    const int h8 = r & 7, ck = (r >> 3) & 15, b = r >> 7;
    float* sv = smem;          // style vector [512]
    float* pr = smem + 512;    // partials [32 rows][8 segs]
    float* sl = smem + 768;    // s_local [32]
    for (int i = t; i < 512; i += 256) sv[i] = ldf(style, b*512 + i, isbf);
    __syncthreads();
    const float inv = 0.04419417382415922f;
    {
      const int row = t >> 3, seg = t & 7;
      const int ci = ck*32 + row;
      const float* svp = sv + seg*64;
      float partial = 0.f;
      if (isbf) {
        const u16* wr = (const u16*)mod_w + (size_t)ci*512 + seg*64;
        #pragma unroll
        for (int k = 0; k < 64; ++k) partial += bf2f(wr[k]) * svp[k];
      } else {
        const float4* wr = (const float4*)((const float*)mod_w + (size_t)ci*512 + seg*64);
        #pragma unroll
        for (int k = 0; k < 16; ++k) {
          float4 p = wr[k];
          partial += p.x*svp[k*4+0] + p.y*svp[k*4+1] + p.z*svp[k*4+2] + p.w*svp[k*4+3];
        }
      }
      pr[t] = partial;
    }
    __syncthreads();
    if (t < 32) {
      float a = 0.f;
      #pragma unroll
      for (int g = 0; g < 8; ++g) a += pr[t*8 + g];
      sl[t] = a * inv + ldf(mod_b, ck*32 + t, isbf);
    }
    __syncthreads();
    const int w = t & 63, cq = t >> 6;
    float sreg[8];
    #pragma unroll
    for (int j = 0; j < 8; ++j) sreg[j] = sl[cq*8 + j];
    for (int hh = 0; hh < 8; ++hh) {
      const int h = h8*8 + hh;
      float f[8];
      #pragma unroll
      for (int j = 0; j < 8; ++j) {
        float xv = ldf(x, (((b*512) + ck*32 + cq*8 + j)*64 + h)*64 + w, isbf);
        f[j] = xv * sreg[j];
      }
      u32 outp[4];
      #pragma unroll
      for (int i = 0; i < 4; ++i)
        outp[i] = (u32)f2bf(f[2*i]) | ((u32)f2bf(f[2*i+1]) << 16);
      uint4 po = {outp[0], outp[1], outp[2], outp[3]};
      *(uint4*)&xT[((size_t)(((b*16 + ck)*64 + h)*256) + t)*8] = po;
    }
  }
}

// ---------------- K2: MFMA conv: double-buffered xs DMA + global-direct weights ----------------
// R10 post-mortem: in-kernel epilogue fusion costs +70us (3rd confirmation) — unfused.
// New structure vs R9 (135us, 61% of binding pipe):
//  (1) af weight fragments load PER-LANE FROM GLOBAL wT (L2-resident, 256B-coalesced) —
//      VMEM pipe instead of LDS pipe. LDS read traffic/CU drops 33% (13.8k->9.2k b128),
//      and the compiler freely hoists these long-latency loads across taps (the cross-tap
//      pipelining ds_reads never got: R5/R7).
//  (2) wsm freed -> xs DOUBLE-BUFFERED (2x77184 B + 1KB dummy sink = 155.4KB <= 160K):
//      STAGE_X(ck+1) issues BEFORE compute(ck); counted s_waitcnt vmcnt(9) drains only the
//      OLDER tile's 9 DMAs, leaving the new 9 in flight under compute. The 72KB x-stage —
//      previously fully exposed per ck — now hides entirely.
//  OOB halo slices redirect to a dummy LDS sink so every wave issues exactly 9 DMAs
//  (keeps the vmcnt(9) count exact; OOB xs rows stay zero from the prologue memset).
// Block 512 thr / 8 waves = 64 co x 16 h x 64 w (0.375 LDS-reads/MFMA -> now 0.25).
// Grid 256 = 1/CU, XCD-chunked (b = bid&7). 2 barriers/ck (same as R9).
__global__ __launch_bounds__(512, 2) void conv_kernel(const u16* __restrict__ xT, const u16* __restrict__ wT,
                                                      float* __restrict__ y, float* __restrict__ part) {
  __shared__ __align__(16) u16 xs[(2*4824 + 64)*8];   // 2 x 77184 B + 1KB dummy = 155392 B
  const int tid = threadIdx.x;
  const int lane = tid & 63;
  const int wid = tid >> 6;            // 0..7
  const int bid = blockIdx.x;
  const int b = bid & 7, ctb = (bid >> 3) & 7, hb = bid >> 6;  // XCD-chunk: xcd = bid%8 = b
  const int ct0 = ctb * 64;
  const int h0 = hb * 16;
  const int m = lane & 15, qd = lane >> 4;

  // zero BOTH xs buffers once: halo cells (c=0,65,66) + never-staged OOB rows stay zero
  {
    uint4 z = {0,0,0,0};
    for (int i = tid; i < 9648; i += 512) *(uint4*)&xs[i*8] = z;
  }

  floatx4 acc[4][8];
  #pragma unroll
  for (int i = 0; i < 4; ++i) {
    #pragma unroll
    for (int j = 0; j < 8; ++j) acc[i][j] = (floatx4)(0.f);
  }

  // stage x(ckn) into buffer bn: 72 lane-linear slices, 9 per wave, ALWAYS 9 issued
  // (OOB rows -> dummy sink at cell 9648; src clamped to a valid address)
  #define STAGE_X(ckn, bn)                                                                 \
    {                                                                                      \
      u16* xb = &xs[(bn)*4824*8];                                                          \
      u16* dum = &xs[9648*8];                                                              \
      for (int sl = wid; sl < 72; sl += 8) {                                               \
        int dr = sl >> 2, q = sl & 3;                                                      \
        int hin = h0 + dr - 1;                                                             \
        int valid = (hin >= 0 && hin <= 63);                                               \
        const u16* src = xT + ((size_t)(((b*16 + (ckn))*64 + (valid ? hin : 0))*256        \
                                        + q*64 + lane))*8;                                 \
        gl16(src, valid ? &xb[((dr*4 + q)*67 + 1)*8] : dum);                               \
      }                                                                                    \
    }

  __syncthreads();             // zeros in LDS before any DMA lands around them
  STAGE_X(0, 0);
  asm volatile("s_waitcnt vmcnt(0)" ::: "memory");
  __syncthreads();             // xs buffer 0 ready

  for (int ck = 0; ck < 16; ++ck) {
    const int buf = ck & 1;
    if (ck < 15) {
      STAGE_X(ck + 1, buf ^ 1);                         // 9 DMAs into the other buffer
      asm volatile("s_waitcnt vmcnt(9)" ::: "memory");  // drain X(ck) (older), keep X(ck+1) flying
    } else {
      asm volatile("s_waitcnt vmcnt(0)" ::: "memory");  // last tile: nothing newer
    }
    __syncthreads();           // all waves' X(ck) landed

    const u16* xb = &xs[buf*4824*8];
    const u16* wtg = wT + ((size_t)(ck*8 + ctb))*2304*8;   // this ck's weight cells (global)
    #pragma unroll
    for (int tap = 0; tap < 9; ++tap) {
      const int k1 = tap / 3, k2 = tap - k1*3;
      short8 af[4], bfr[8];
      #pragma unroll
      for (int mi = 0; mi < 4; ++mi)
        af[mi] = *(const short8*)&wtg[((tap*4 + qd)*64 + mi*16 + m)*8];   // global, coalesced
      #pragma unroll
      for (int hh = 0; hh < 2; ++hh) {
        const int dr = wid*2 + hh + k1;       // 0..17
        #pragma unroll
        for (int nw = 0; nw < 4; ++nw)
          bfr[hh*4 + nw] = *(const short8*)&xb[((dr*4 + qd)*67 + nw*16 + m + k2)*8];
      }
      #pragma unroll
      for (int ni = 0; ni < 8; ++ni) {
        #pragma unroll
        for (int mi = 0; mi < 4; ++mi)
          acc[mi][ni] = __builtin_amdgcn_mfma_f32_16x16x32_bf16(af[mi], bfr[ni], acc[mi][ni], 0, 0, 0);
      }
    }
    __syncthreads();           // compute(ck) done: buf free for iter ck+1's stage target
  }
  #undef STAGE_X

  // write y (pre-norm conv result, f32) into d_out
  #pragma unroll
  for (int mi = 0; mi < 4; ++mi) {
    #pragma unroll
    for (int hh = 0; hh < 2; ++hh) {
      const int h = h0 + wid*2 + hh;
      #pragma unroll
      for (int nw = 0; nw < 4; ++nw) {
        #pragma unroll
        for (int r = 0; r < 4; ++r) {
          int co = ct0 + mi*16 + qd*4 + r;    // C/D: row=(lane>>4)*4+reg, col=lane&15
          int w = nw*16 + m;
          y[(size_t)(((b*512) + co)*64 + h)*64 + w] = acc[mi][hh*4 + nw][r];
        }
      }
    }
  }

  // fused IN partials: per-cout sum / sumsq over this block's 16x64 tile
  float s1[16], s2[16];
  #pragma unroll
  for (int mi = 0; mi < 4; ++mi) {
    #pragma unroll
    for (int r = 0; r < 4; ++r) {
      float a = 0.f, aa = 0.f;
      #pragma unroll
      for (int ni = 0; ni < 8; ++ni) {
        float v = acc[mi][ni][r];
        a += v; aa += v*v;
      }
      s1[mi*4+r] = a; s2[mi*4+r] = aa;
    }
  }
  #pragma unroll
  for (int off = 1; off < 16; off <<= 1) {
    #pragma unroll
    for (int i = 0; i < 16; ++i) {
      s1[i] += __shfl_xor(s1[i], off, 64);
      s2[i] += __shfl_xor(s2[i], off, 64);
    }
  }
  float* red = (float*)xs;         // reuse LDS (post-loop barrier passed): [wid8][co64][2]
  if (m == 0) {
    #pragma unroll
    for (int mi = 0; mi < 4; ++mi) {
      #pragma unroll
      for (int r = 0; r < 4; ++r) {
        int co = mi*16 + qd*4 + r;
        red[(wid*64 + co)*2 + 0] = s1[mi*4+r];
        red[(wid*64 + co)*2 + 1] = s2[mi*4+r];
      }
    }
  }
  __syncthreads();
  if (tid < 128) {
    int co = tid >> 1, which = tid & 1;
    float v = 0.f;
    #pragma unroll
    for (int w8 = 0; w8 < 8; ++w8) v += red[(w8*64 + co)*2 + which];
    part[(size_t)(((b*4 + hb)*512) + ct0 + co)*2 + which] = v;
  }
}

// ---------------- K3: finalize + normalize + CLADE (R9 verified) ----------------
__global__ __launch_bounds__(256) void epi_kernel(float* __restrict__ y, const float* __restrict__ part,
                                                  const float* __restrict__ s, const float* __restrict__ wsqT2,
                                                  const float* __restrict__ cw, const float* __restrict__ cb,
                                                  const int* __restrict__ label) {
  const int bc = blockIdx.x;           // 4096 = b*512+co
  const int b = bc >> 9, co = bc & 511;
  const int t = threadIdx.x;
  __shared__ float tabw[35], tabb[35];
  __shared__ float redp[4];
  __shared__ float2 msh;
  if (t < 35) { tabw[t] = cw[t*512 + co]; tabb[t] = cb[t*512 + co]; }

  // SS partial: thread t covers ci = t, t+256 (coalesced)
  const float* sb = s + b*512;
  const float* wq = wsqT2 + (size_t)co*512;
  float ep;
  {
    float s0 = sb[t], s1v = sb[t + 256];
    ep = s0*s0*wq[t] + s1v*s1v*wq[t + 256];
  }
  #pragma unroll
  for (int off = 1; off < 64; off <<= 1) ep += __shfl_xor(ep, off, 64);
  if ((t & 63) == 0) redp[t >> 6] = ep;
  __syncthreads();
  if (t == 0) {
    float SS = redp[0] + redp[1] + redp[2] + redp[3];
    float S = 0.f, Q = 0.f;
    const float2* pv = (const float2*)part;
    #pragma unroll
    for (int hb = 0; hb < 4; ++hb) {
      float2 p = pv[(size_t)((b*4 + hb)*512) + co];
      S += p.x; Q += p.y;
    }
    float mval = S * (1.f/4096.f);
    float var = fmaxf(Q * (1.f/4096.f) - mval*mval, 0.f);
    float eps = 1e-5f*SS + 4.608e-10f;   // = eps_in/(scale*demod)^2, exact
    msh = make_float2(mval, rsqrtf(var + eps));
  }
  __syncthreads();
  const float mval = msh.x, is = msh.y;

  float* yp = y + (size_t)bc*4096 + t*16;
  const int* lp = label + b*4096 + t*16;
  #pragma unroll
  for (int u = 0; u < 4; ++u) {
    float4 v = *(const float4*)(yp + u*4);
    int4 l = *(const int4*)(lp + u*4);
    float4 o;
    o.x = (v.x - mval)*is*tabw[l.x] + tabb[l.x];
    o.y = (v.y - mval)*is*tabw[l.y] + tabb[l.y];
    o.z = (v.z - mval)*is*tabw[l.z] + tabb[l.z];
    o.w = (v.w - mval)*is*tabw[l.w] + tabb[l.w];
    *(float4*)(yp + u*4) = o;
  }
}

extern "C" void kernel_launch(void* const* d_in, const int* in_sizes, int n_in,
                              void* d_out, int out_size, void* d_ws, size_t ws_size,
                              hipStream_t stream) {
  (void)in_sizes; (void)n_in; (void)out_size; (void)ws_size;
  const void* input       = d_in[0];
  const void* style       = d_in[1];
  const void* class_style = d_in[2];
  const void* weight      = d_in[3];
  const void* mod_w       = d_in[4];
  const void* mod_b       = d_in[5];
  const void* cw_w        = d_in[6];
  const void* cw_b        = d_in[7];
  const void* cb_w        = d_in[8];
  const void* cb_b        = d_in[9];
  const int* label        = (const int*)d_in[10];
  float* y = (float*)d_out;                   // f32 conv result in d_out, normalized in place

  char* ws = (char*)d_ws;
  u16*   xT    = (u16*)  (ws + 0);            // 33,554,432 B  [b][ck16][h][q4][w64] bf16 cells
  u16*   wT    = (u16*)  (ws + 33554432);     //  4,718,592 B  [ck16][ctb8][2304 cells] bf16
  float* wsqT2 = (float*)(ws + 38273024);     //  1,048,576 B  [cout][cin]
  float* s     = (float*)(ws + 39321600);     //     16,384 B  [b][ci]
  float* cw    = (float*)(ws + 39337984);     //     71,680 B  [ncls][cout]
  float* cb    = (float*)(ws + 39409664);     //     71,680 B
  float* part  = (float*)(ws + 39481344);     //    131,072 B  [b][hb4][cout][2]  (total 39,612,416 B)

  hipLaunchKernelGGL(prep_kernel, dim3(1614), dim3(256), 0, stream,
                     style, class_style, weight, mod_w, mod_b, cw_w, cw_b, cb_w, cb_b,
                     input, s, cw, cb, wT, wsqT2, xT);
  hipLaunchKernelGGL(conv_kernel, dim3(256), dim3(512), 0, stream, xT, wT, y, part);
  hipLaunchKernelGGL(epi_kernel, dim3(4096), dim3(256), 0, stream, y, part, s, wsqT2, cw, cb, label);
}

// Round 13
// 315.716 us; speedup vs baseline: 1.0258x; 1.0258x over previous
//
#include <hip/hip_runtime.h>

typedef unsigned short u16;
typedef unsigned int u32;
typedef __attribute__((ext_vector_type(8))) short short8;
typedef __attribute__((ext_vector_type(4))) float floatx4;

typedef const u32 __attribute__((address_space(1))) glb_u32;
typedef u32 __attribute__((address_space(3))) lds_u32;

__device__ inline float bf2f(u16 h) {
  union { u32 u; float f; } v; v.u = ((u32)h) << 16; return v.f;
}
__device__ inline u16 f2bf(float f) {
  union { float f; u32 u; } v; v.f = f;
  u32 u = v.u;
  return (u16)((u + 0x7fffu + ((u >> 16) & 1u)) >> 16);
}
// dtype-generic load: isbf is wave-uniform (from per-block sniffer)
__device__ inline float ldf(const void* p, int i, int isbf) {
  return isbf ? bf2f(((const u16*)p)[i]) : ((const float*)p)[i];
}
// async global->LDS DMA: 16B/lane, dest = wave-uniform base + lane*16, src per-lane
__device__ inline void gl16(const void* g, void* l) {
  __builtin_amdgcn_global_load_lds((glb_u32*)g, (lds_u32*)l, 16, 0, 0);
}

// ---------------- K1: fused prep ----------------
// One kernel, 1614 blocks, three roles (block-uniform branch):
//   [0,78)      styles rows  -> s[8][512], cw[35][512], cb[35][512]
//   [78,590)    wprep        -> wT[ck][ctblk][(tap*4+q)*64+co] cells, wsqT2[co][ci]
//   [590,1614)  xtrans       -> xT[b][ck][h][q][w] bf16 cells; block per (b,ck,h8).
//                               R13: keeps ONLY R12's IO vectorization (float4 x-reads
//                               along w, 64B contiguous stores — pure width change,
//                               same thread->cell bijection, barriers unchanged).
__global__ __launch_bounds__(256) void prep_kernel(
    const void* __restrict__ style, const void* __restrict__ class_style,
    const void* __restrict__ weight,
    const void* __restrict__ mod_w, const void* __restrict__ mod_b,
    const void* __restrict__ cw_w, const void* __restrict__ cw_b,
    const void* __restrict__ cb_w, const void* __restrict__ cb_b,
    const void* __restrict__ x,
    float* __restrict__ s, float* __restrict__ cw, float* __restrict__ cb,
    u16* __restrict__ wT, float* __restrict__ wsqT2, u16* __restrict__ xT) {
  __shared__ float smem[4608];       // union: styles v[512] | wprep wsmem[4608] | xtrans sv[512]+pr[256]+sl[32]
  __shared__ int cnt;
  const int t = threadIdx.x;

  if (t == 0) cnt = 0;
  __syncthreads();
  {
    u32 v = ((const u32*)weight)[1024 + t];
    int e = (v >> 7) & 0xFF;
    if (e >= 96 && e <= 160) atomicAdd(&cnt, 1);
  }
  __syncthreads();
  const int isbf = (cnt >= 154) ? 1 : 0;
  const int bid = blockIdx.x;

  if (bid < 78) {
    // ---- styles role ----
    int row = bid;
    const void *vec, *wm, *bias; float* out; int voff;
    if (row < 8)        { vec = style;       voff = row*512;      wm = mod_w; bias = mod_b; out = s  + row*512; }
    else if (row < 43)  { vec = class_style; voff = (row-8)*512;  wm = cw_w;  bias = cw_b;  out = cw + (row-8)*512; }
    else                { vec = class_style; voff = (row-43)*512; wm = cb_w;  bias = cb_b;  out = cb + (row-43)*512; }
    float* v = smem;
    for (int i = t; i < 512; i += 256) v[i] = ldf(vec, voff + i, isbf);
    __syncthreads();
    const float inv = 0.04419417382415922f;  // 1/sqrt(512)
    for (int o = t; o < 512; o += 256) {
      float acc = 0.f;
      if (isbf) {
        for (int k = 0; k < 512; ++k) acc += bf2f(((const u16*)wm)[o*512 + k]) * v[k];
      } else {
        const float4* wr = (const float4*)((const float*)wm + o*512);
        for (int k = 0; k < 128; ++k) {
          float4 p = wr[k];
          acc += p.x*v[k*4+0] + p.y*v[k*4+1] + p.z*v[k*4+2] + p.w*v[k*4+3];
        }
      }
      out[o] = acc * inv + ldf(bias, o, isbf);
    }
  } else if (bid < 590) {
    // ---- wprep role ----
    const int co = bid - 78;
    const int ctb = co >> 6, col = co & 63;
    float* wsmem = smem;
    for (int i = t; i < 4608; i += 256)
      wsmem[i] = ldf(weight, co*4608 + i, isbf);   // coalesced
    __syncthreads();
    for (int ci = t; ci < 512; ci += 256) {
      float sq = 0.f;
      const int ck = ci >> 5, q = (ci >> 3) & 3, e = ci & 7;
      #pragma unroll
      for (int tap = 0; tap < 9; ++tap) {
        float fv = wsmem[ci*9 + tap];
        sq += fv*fv;
        wT[((size_t)(ck*8 + ctb)*2304 + (tap*4 + q)*64 + col)*8 + e] = f2bf(fv);
      }
      wsqT2[(size_t)co*512 + ci] = sq;             // coalesced store
    }
  } else {
    // ---- xtrans role: block per (b, ck, h8); s once per 8 h rows; vectorized IO ----
    const int r = bid - 590;
    const int h8 = r & 7, ck = (r >> 3) & 15, b = r >> 7;
    float* sv = smem;          // style vector [512]
    float* pr = smem + 512;    // partials [32 rows][8 segs]
    float* sl = smem + 768;    // s_local [32]
    for (int i = t; i < 512; i += 256) sv[i] = ldf(style, b*512 + i, isbf);
    __syncthreads();
    const float inv = 0.04419417382415922f;
    {
      const int row = t >> 3, seg = t & 7;
      const int ci = ck*32 + row;
      const float* svp = sv + seg*64;
      float partial = 0.f;
      if (isbf) {
        const u16* wr = (const u16*)mod_w + (size_t)ci*512 + seg*64;
        #pragma unroll
        for (int k = 0; k < 64; ++k) partial += bf2f(wr[k]) * svp[k];
      } else {
        const float4* wr = (const float4*)((const float*)mod_w + (size_t)ci*512 + seg*64);
        #pragma unroll
        for (int k = 0; k < 16; ++k) {
          float4 p = wr[k];
          partial += p.x*svp[k*4+0] + p.y*svp[k*4+1] + p.z*svp[k*4+2] + p.w*svp[k*4+3];
        }
      }
      pr[t] = partial;
    }
    __syncthreads();
    if (t < 32) {
      float a = 0.f;
      #pragma unroll
      for (int g = 0; g < 8; ++g) a += pr[t*8 + g];
      sl[t] = a * inv + ldf(mod_b, ck*32 + t, isbf);
    }
    __syncthreads();
    // thread = (wq 16, cq 4, hg 4): 4 w-columns x 8 ci at h = h8*8 + it*4 + hg
    const int wq = t & 15, cq = (t >> 4) & 3, hg = t >> 6;
    float sreg[8];
    #pragma unroll
    for (int j = 0; j < 8; ++j) sreg[j] = sl[cq*8 + j];
    #pragma unroll
    for (int it = 0; it < 2; ++it) {
      const int h = h8*8 + it*4 + hg;
      float f[8][4];
      if (isbf) {
        #pragma unroll
        for (int j = 0; j < 8; ++j) {
          const u16* xp = (const u16*)x + ((size_t)(((b*512) + ck*32 + cq*8 + j)*64 + h)*64 + wq*4);
          ushort4 v = *(const ushort4*)xp;
          f[j][0] = bf2f(v.x); f[j][1] = bf2f(v.y); f[j][2] = bf2f(v.z); f[j][3] = bf2f(v.w);
        }
      } else {
        #pragma unroll
        for (int j = 0; j < 8; ++j) {
          const float* xp = (const float*)x + ((size_t)(((b*512) + ck*32 + cq*8 + j)*64 + h)*64 + wq*4);
          float4 v = *(const float4*)xp;
          f[j][0] = v.x; f[j][1] = v.y; f[j][2] = v.z; f[j][3] = v.w;
        }
      }
      u16* xrow = xT + (size_t)(((b*16 + ck)*64 + h)*256)*8;
      #pragma unroll
      for (int wk = 0; wk < 4; ++wk) {
        u32 outp[4];
        #pragma unroll
        for (int i = 0; i < 4; ++i)
          outp[i] = (u32)f2bf(f[2*i][wk]*sreg[2*i]) | ((u32)f2bf(f[2*i+1][wk]*sreg[2*i+1]) << 16);
        uint4 po = {outp[0], outp[1], outp[2], outp[3]};
        *(uint4*)&xrow[(size_t)(cq*64 + wq*4 + wk)*8] = po;   // cell = q*64 + w (unchanged)
      }
    }
  }
}

// ---------------- K2: MFMA conv (R9 verified form, 133-137us, replay-proven) ----------------
// Per ck: {barrier, STAGE_X via gl16, vmcnt(0), barrier, STAGE_W(ck+1) prefetch, 9 taps}.
// Block 512 thr / 8 waves = 64 co x 16 h x 64 w (0.375 ds_reads/MFMA). Grid 256 = 1/CU,
// XCD-chunked (b = bid&7). LDS: xs [dr18][q4][c67] 77184 B + wsm 2x36864 B = 150912 B.
__global__ __launch_bounds__(512, 2) void conv_kernel(const u16* __restrict__ xT, const u16* __restrict__ wT,
                                                      float* __restrict__ y, float* __restrict__ part) {
  __shared__ __align__(16) u16 xs[18*4*67*8];    // 77184 B
  __shared__ __align__(16) u16 wsm[2*2304*8];    // 73728 B
  const int tid = threadIdx.x;
  const int lane = tid & 63;
  const int wid = tid >> 6;            // 0..7
  const int bid = blockIdx.x;
  const int b = bid & 7, ctb = (bid >> 3) & 7, hb = bid >> 6;  // XCD-chunk: xcd = bid%8 = b
  const int ct0 = ctb * 64;
  const int h0 = hb * 16;
  const int m = lane & 15, qd = lane >> 4;

  // zero xs once: halo cells (c=0,65,66) + never-staged rows (dr=0 @hb=0, dr=17 @hb=3)
  {
    uint4 z = {0,0,0,0};
    for (int i = tid; i < 4824; i += 512) *(uint4*)&xs[i*8] = z;
  }

  floatx4 acc[4][8];
  #pragma unroll
  for (int i = 0; i < 4; ++i) {
    #pragma unroll
    for (int j = 0; j < 8; ++j) acc[i][j] = (floatx4)(0.f);
  }

  // stage x(ck): 72 lane-linear slices (18 dr x 4 q), 9 per wave
  #define STAGE_X(ckn)                                                                     \
    for (int sl = wid; sl < 72; sl += 8) {                                                 \
      int dr = sl >> 2, q = sl & 3;                                                        \
      int hin = h0 + dr - 1;                                                               \
      if (hin >= 0 && hin <= 63) {                                                         \
        const u16* src = xT + ((size_t)(((b*16 + (ckn))*64 + hin)*256 + q*64 + lane))*8;   \
        gl16(src, &xs[((dr*4 + q)*67 + 1)*8]);                                             \
      }                                                                                    \
    }
  // stage w(ck) into buffer bn: 36 lane-linear slices
  #define STAGE_W(ckn, bn)                                                                 \
    for (int j = wid; j < 36; j += 8) {                                                    \
      const u16* src = wT + ((size_t)(((ckn)*8 + ctb)*2304 + j*64 + lane))*8;              \
      gl16(src, &wsm[((bn)*2304 + j*64)*8]);                                               \
    }

  __syncthreads();             // zeros in LDS before any DMA lands around them
  STAGE_W(0, 0);               // wsm(0) prefetch; drained by first in-loop vmcnt

  for (int ck = 0; ck < 16; ++ck) {
    const int buf = ck & 1;
    __syncthreads();           // compute(ck-1) done: xs free, wsm[buf^1] free

    STAGE_X(ck);
    asm volatile("s_waitcnt vmcnt(0)" ::: "memory");  // xs(ck) + own wsm(ck) DMAs complete
    __syncthreads();           // all waves' stages visible

    if (ck < 15) STAGE_W(ck + 1, buf ^ 1);   // prefetch next weights under compute(ck)

    const u16* wb = &wsm[buf*2304*8];
    #pragma unroll
    for (int tap = 0; tap < 9; ++tap) {
      const int k1 = tap / 3, k2 = tap - k1*3;
      short8 af[4], bfr[8];
      #pragma unroll
      for (int mi = 0; mi < 4; ++mi)
        af[mi] = *(const short8*)&wb[((tap*4 + qd)*64 + mi*16 + m)*8];
      #pragma unroll
      for (int hh = 0; hh < 2; ++hh) {
        const int dr = wid*2 + hh + k1;       // 0..17
        #pragma unroll
        for (int nw = 0; nw < 4; ++nw)
          bfr[hh*4 + nw] = *(const short8*)&xs[((dr*4 + qd)*67 + nw*16 + m + k2)*8];
      }
      #pragma unroll
      for (int ni = 0; ni < 8; ++ni) {
        #pragma unroll
        for (int mi = 0; mi < 4; ++mi)
          acc[mi][ni] = __builtin_amdgcn_mfma_f32_16x16x32_bf16(af[mi], bfr[ni], acc[mi][ni], 0, 0, 0);
      }
    }
  }
  #undef STAGE_X
  #undef STAGE_W

  // write y (pre-norm conv result, f32) into d_out
  #pragma unroll
  for (int mi = 0; mi < 4; ++mi) {
    #pragma unroll
    for (int hh = 0; hh < 2; ++hh) {
      const int h = h0 + wid*2 + hh;
      #pragma unroll
      for (int nw = 0; nw < 4; ++nw) {
        #pragma unroll
        for (int r = 0; r < 4; ++r) {
          int co = ct0 + mi*16 + qd*4 + r;    // C/D: row=(lane>>4)*4+reg, col=lane&15
          int w = nw*16 + m;
          y[(size_t)(((b*512) + co)*64 + h)*64 + w] = acc[mi][hh*4 + nw][r];
        }
      }
    }
  }

  // fused IN partials: per-cout sum / sumsq over this block's 16x64 tile
  float s1[16], s2[16];
  #pragma unroll
  for (int mi = 0; mi < 4; ++mi) {
    #pragma unroll
    for (int r = 0; r < 4; ++r) {
      float a = 0.f, aa = 0.f;
      #pragma unroll
      for (int ni = 0; ni < 8; ++ni) {
        float v = acc[mi][ni][r];
        a += v; aa += v*v;
      }
      s1[mi*4+r] = a; s2[mi*4+r] = aa;
    }
  }
  #pragma unroll
  for (int off = 1; off < 16; off <<= 1) {
    #pragma unroll
    for (int i = 0; i < 16; ++i) {
      s1[i] += __shfl_xor(s1[i], off, 64);
      s2[i] += __shfl_xor(s2[i], off, 64);
    }
  }
  __syncthreads();                 // all waves done reading xs for MFMA
  float* red = (float*)xs;         // reuse LDS: [wid8][co64][2] = 1024 floats
  if (m == 0) {
    #pragma unroll
    for (int mi = 0; mi < 4; ++mi) {
      #pragma unroll
      for (int r = 0; r < 4; ++r) {
        int co = mi*16 + qd*4 + r;
        red[(wid*64 + co)*2 + 0] = s1[mi*4+r];
        red[(wid*64 + co)*2 + 1] = s2[mi*4+r];
      }
    }
  }
  __syncthreads();
  if (tid < 128) {
    int co = tid >> 1, which = tid & 1;
    float v = 0.f;
    #pragma unroll
    for (int w8 = 0; w8 < 8; ++w8) v += red[(w8*64 + co)*2 + which];
    part[(size_t)(((b*4 + hb)*512) + ct0 + co)*2 + which] = v;
  }
}

// ---------------- K3: finalize + normalize + CLADE (R9 exact, replay-proven) ----------------
__global__ __launch_bounds__(256) void epi_kernel(float* __restrict__ y, const float* __restrict__ part,
                                                  const float* __restrict__ s, const float* __restrict__ wsqT2,
                                                  const float* __restrict__ cw, const float* __restrict__ cb,
                                                  const int* __restrict__ label) {
  const int bc = blockIdx.x;           // 4096 = b*512+co
  const int b = bc >> 9, co = bc & 511;
  const int t = threadIdx.x;
  __shared__ float tabw[35], tabb[35];
  __shared__ float redp[4];
  __shared__ float2 msh;
  if (t < 35) { tabw[t] = cw[t*512 + co]; tabb[t] = cb[t*512 + co]; }

  // SS partial: thread t covers ci = t, t+256 (coalesced)
  const float* sb = s + b*512;
  const float* wq = wsqT2 + (size_t)co*512;
  float ep;
  {
    float s0 = sb[t], s1v = sb[t + 256];
    ep = s0*s0*wq[t] + s1v*s1v*wq[t + 256];
  }
  #pragma unroll
  for (int off = 1; off < 64; off <<= 1) ep += __shfl_xor(ep, off, 64);
  if ((t & 63) == 0) redp[t >> 6] = ep;
  __syncthreads();
  if (t == 0) {
    float SS = redp[0] + redp[1] + redp[2] + redp[3];
    float S = 0.f, Q = 0.f;
    const float2* pv = (const float2*)part;
    #pragma unroll
    for (int hb = 0; hb < 4; ++hb) {
      float2 p = pv[(size_t)((b*4 + hb)*512) + co];
      S += p.x; Q += p.y;
    }
    float mval = S * (1.f/4096.f);
    float var = fmaxf(Q * (1.f/4096.f) - mval*mval, 0.f);
    float eps = 1e-5f*SS + 4.608e-10f;   // = eps_in/(scale*demod)^2, exact
    msh = make_float2(mval, rsqrtf(var + eps));
  }
  __syncthreads();
  const float mval = msh.x, is = msh.y;

  float* yp = y + (size_t)bc*4096 + t*16;
  const int* lp = label + b*4096 + t*16;
  #pragma unroll
  for (int u = 0; u < 4; ++u) {
    float4 v = *(const float4*)(yp + u*4);
    int4 l = *(const int4*)(lp + u*4);
    float4 o;
    o.x = (v.x - mval)*is*tabw[l.x] + tabb[l.x];
    o.y = (v.y - mval)*is*tabw[l.y] + tabb[l.y];
    o.z = (v.z - mval)*is*tabw[l.z] + tabb[l.z];
    o.w = (v.w - mval)*is*tabw[l.w] + tabb[l.w];
    *(float4*)(yp + u*4) = o;
  }
}

extern "C" void kernel_launch(void* const* d_in, const int* in_sizes, int n_in,
                              void* d_out, int out_size, void* d_ws, size_t ws_size,
                              hipStream_t stream) {
  (void)in_sizes; (void)n_in; (void)out_size; (void)ws_size;
  const void* input       = d_in[0];
  const void* style       = d_in[1];
  const void* class_style = d_in[2];
  const void* weight      = d_in[3];
  const void* mod_w       = d_in[4];
  const void* mod_b       = d_in[5];
  const void* cw_w        = d_in[6];
  const void* cw_b        = d_in[7];
  const void* cb_w        = d_in[8];
  const void* cb_b        = d_in[9];
  const int* label        = (const int*)d_in[10];
  float* y = (float*)d_out;                   // f32 conv result in d_out, normalized in place

  char* ws = (char*)d_ws;
  u16*   xT    = (u16*)  (ws + 0);            // 33,554,432 B  [b][ck16][h][q4][w64] bf16 cells
  u16*   wT    = (u16*)  (ws + 33554432);     //  4,718,592 B  [ck16][ctb8][2304 cells] bf16
  float* wsqT2 = (float*)(ws + 38273024);     //  1,048,576 B  [cout][cin]
  float* s     = (float*)(ws + 39321600);     //     16,384 B  [b][ci]
  float* cw    = (float*)(ws + 39337984);     //     71,680 B  [ncls][cout]
  float* cb    = (float*)(ws + 39409664);     //     71,680 B
  float* part  = (float*)(ws + 39481344);     //    131,072 B  [b][hb4][cout][2]  (total 39,612,416 B)

  hipLaunchKernelGGL(prep_kernel, dim3(1614), dim3(256), 0, stream,
                     style, class_style, weight, mod_w, mod_b, cw_w, cw_b, cb_w, cb_b,
                     input, s, cw, cb, wT, wsqT2, xT);
  hipLaunchKernelGGL(conv_kernel, dim3(256), dim3(512), 0, stream, xT, wT, y, part);
  hipLaunchKernelGGL(epi_kernel, dim3(4096), dim3(256), 0, stream, y, part, s, wsqT2, cw, cb, label);
}

// Round 14
// 307.072 us; speedup vs baseline: 1.0547x; 1.0281x over previous
//
#include <hip/hip_runtime.h>

typedef unsigned short u16;
typedef unsigned int u32;
typedef __attribute__((ext_vector_type(8))) short short8;
typedef __attribute__((ext_vector_type(4))) float floatx4;

typedef const u32 __attribute__((address_space(1))) glb_u32;
typedef u32 __attribute__((address_space(3))) lds_u32;

__device__ inline float bf2f(u16 h) {
  union { u32 u; float f; } v; v.u = ((u32)h) << 16; return v.f;
}
__device__ inline u16 f2bf(float f) {
  union { float f; u32 u; } v; v.f = f;
  u32 u = v.u;
  return (u16)((u + 0x7fffu + ((u >> 16) & 1u)) >> 16);
}
// dtype-generic load: isbf is wave-uniform (from per-block sniffer)
__device__ inline float ldf(const void* p, int i, int isbf) {
  return isbf ? bf2f(((const u16*)p)[i]) : ((const float*)p)[i];
}
// async global->LDS DMA: 16B/lane, dest = wave-uniform base + lane*16, src per-lane
__device__ inline void gl16(const void* g, void* l) {
  __builtin_amdgcn_global_load_lds((glb_u32*)g, (lds_u32*)l, 16, 0, 0);
}

// ---------------- K1: fused prep ----------------
// One kernel, 1614 blocks, three roles (block-uniform branch):
//   [0,78)      styles rows  -> s[8][512], cw[35][512], cb[35][512]
//   [78,590)    wprep        -> wT[ck][ctblk][(tap*4+q)*64+co] cells, wsqT2[co][ci]
//   [590,1614)  xtrans       -> xT[b][ck][h][q][w] bf16 cells; block per (b,ck,h8).
// R14: ALL isbf loads vectorized to short8 (16B) — mod_w dots, weight staging, x reads
// (G13: bf16 scalar loads cost 2-2.5x). Same cell bijection; f32 paths unchanged;
// conv/epi byte-identical to R13 (replay-proven).
__global__ __launch_bounds__(256) void prep_kernel(
    const void* __restrict__ style, const void* __restrict__ class_style,
    const void* __restrict__ weight,
    const void* __restrict__ mod_w, const void* __restrict__ mod_b,
    const void* __restrict__ cw_w, const void* __restrict__ cw_b,
    const void* __restrict__ cb_w, const void* __restrict__ cb_b,
    const void* __restrict__ x,
    float* __restrict__ s, float* __restrict__ cw, float* __restrict__ cb,
    u16* __restrict__ wT, float* __restrict__ wsqT2, u16* __restrict__ xT) {
  __shared__ float smem[4608];       // union: styles v[512] | wprep wsmem[4608] | xtrans sv[512]+pr[256]+sl[32]
  __shared__ int cnt;
  const int t = threadIdx.x;

  if (t == 0) cnt = 0;
  __syncthreads();
  {
    u32 v = ((const u32*)weight)[1024 + t];
    int e = (v >> 7) & 0xFF;
    if (e >= 96 && e <= 160) atomicAdd(&cnt, 1);
  }
  __syncthreads();
  const int isbf = (cnt >= 154) ? 1 : 0;
  const int bid = blockIdx.x;

  if (bid < 78) {
    // ---- styles role ----
    int row = bid;
    const void *vec, *wm, *bias; float* out; int voff;
    if (row < 8)        { vec = style;       voff = row*512;      wm = mod_w; bias = mod_b; out = s  + row*512; }
    else if (row < 43)  { vec = class_style; voff = (row-8)*512;  wm = cw_w;  bias = cw_b;  out = cw + (row-8)*512; }
    else                { vec = class_style; voff = (row-43)*512; wm = cb_w;  bias = cb_b;  out = cb + (row-43)*512; }
    float* v = smem;
    for (int i = t; i < 512; i += 256) v[i] = ldf(vec, voff + i, isbf);
    __syncthreads();
    const float inv = 0.04419417382415922f;  // 1/sqrt(512)
    for (int o = t; o < 512; o += 256) {
      float acc = 0.f;
      if (isbf) {
        const short8* wr8 = (const short8*)((const u16*)wm + (size_t)o*512);  // 16B-aligned
        for (int k = 0; k < 64; ++k) {
          short8 p = wr8[k];
          #pragma unroll
          for (int e = 0; e < 8; ++e) acc += bf2f((u16)p[e]) * v[k*8 + e];
        }
      } else {
        const float4* wr = (const float4*)((const float*)wm + o*512);
        for (int k = 0; k < 128; ++k) {
          float4 p = wr[k];
          acc += p.x*v[k*4+0] + p.y*v[k*4+1] + p.z*v[k*4+2] + p.w*v[k*4+3];
        }
      }
      out[o] = acc * inv + ldf(bias, o, isbf);
    }
  } else if (bid < 590) {
    // ---- wprep role ----
    const int co = bid - 78;
    const int ctb = co >> 6, col = co & 63;
    float* wsmem = smem;
    if (isbf) {
      const short8* wp = (const short8*)((const u16*)weight + (size_t)co*4608);  // 9216B: 16B-aligned
      for (int i = t; i < 576; i += 256) {
        short8 v = wp[i];
        #pragma unroll
        for (int e = 0; e < 8; ++e) wsmem[i*8 + e] = bf2f((u16)v[e]);
      }
    } else {
      for (int i = t; i < 4608; i += 256)
        wsmem[i] = ((const float*)weight)[co*4608 + i];   // coalesced
    }
    __syncthreads();
    for (int ci = t; ci < 512; ci += 256) {
      float sq = 0.f;
      const int ck = ci >> 5, q = (ci >> 3) & 3, e = ci & 7;
      #pragma unroll
      for (int tap = 0; tap < 9; ++tap) {
        float fv = wsmem[ci*9 + tap];
        sq += fv*fv;
        wT[((size_t)(ck*8 + ctb)*2304 + (tap*4 + q)*64 + col)*8 + e] = f2bf(fv);
      }
      wsqT2[(size_t)co*512 + ci] = sq;             // coalesced store
    }
  } else {
    // ---- xtrans role: block per (b, ck, h8); s once per 8 h rows; vectorized IO ----
    const int r = bid - 590;
    const int h8 = r & 7, ck = (r >> 3) & 15, b = r >> 7;
    float* sv = smem;          // style vector [512]
    float* pr = smem + 512;    // partials [32 rows][8 segs]
    float* sl = smem + 768;    // s_local [32]
    for (int i = t; i < 512; i += 256) sv[i] = ldf(style, b*512 + i, isbf);
    __syncthreads();
    const float inv = 0.04419417382415922f;
    {
      const int row = t >> 3, seg = t & 7;
      const int ci = ck*32 + row;
      const float* svp = sv + seg*64;
      float partial = 0.f;
      if (isbf) {
        const short8* wr8 = (const short8*)((const u16*)mod_w + (size_t)ci*512 + seg*64);  // 128B-aligned
        #pragma unroll
        for (int k8 = 0; k8 < 8; ++k8) {
          short8 p = wr8[k8];
          #pragma unroll
          for (int e = 0; e < 8; ++e) partial += bf2f((u16)p[e]) * svp[k8*8 + e];
        }
      } else {
        const float4* wr = (const float4*)((const float*)mod_w + (size_t)ci*512 + seg*64);
        #pragma unroll
        for (int k = 0; k < 16; ++k) {
          float4 p = wr[k];
          partial += p.x*svp[k*4+0] + p.y*svp[k*4+1] + p.z*svp[k*4+2] + p.w*svp[k*4+3];
        }
      }
      pr[t] = partial;
    }
    __syncthreads();
    if (t < 32) {
      float a = 0.f;
      #pragma unroll
      for (int g = 0; g < 8; ++g) a += pr[t*8 + g];
      sl[t] = a * inv + ldf(mod_b, ck*32 + t, isbf);
    }
    __syncthreads();
    if (isbf) {
      // thread = (w8 8, cq 4, hg 8): 8 w-columns x 8 ci at h = h8*8 + hg; 16B loads,
      // 128B-contiguous stores/thread. Cell bijection: cell cq*64 + w8*8 + wk, slot j = ci j.
      const int w8 = t & 7, cq = (t >> 3) & 3, hg = t >> 5;
      const int h = h8*8 + hg;
      float sreg[8];
      #pragma unroll
      for (int j = 0; j < 8; ++j) sreg[j] = sl[cq*8 + j];
      u16 fb[8][8];
      #pragma unroll
      for (int j = 0; j < 8; ++j) {
        const u16* xp = (const u16*)x + ((size_t)(((b*512) + ck*32 + cq*8 + j)*64 + h)*64 + w8*8);
        short8 v = *(const short8*)xp;     // 16B-aligned
        #pragma unroll
        for (int wk = 0; wk < 8; ++wk) fb[j][wk] = f2bf(bf2f((u16)v[wk]) * sreg[j]);
      }
      u16* xrow = xT + (size_t)(((b*16 + ck)*64 + h)*256)*8;
      #pragma unroll
      for (int wk = 0; wk < 8; ++wk) {
        u32 outp[4];
        #pragma unroll
        for (int i = 0; i < 4; ++i)
          outp[i] = (u32)fb[2*i][wk] | ((u32)fb[2*i+1][wk] << 16);
        uint4 po = {outp[0], outp[1], outp[2], outp[3]};
        *(uint4*)&xrow[(size_t)(cq*64 + w8*8 + wk)*8] = po;
      }
    } else {
      // f32 path: R13 exact (float4 x-reads along w, 64B contiguous stores)
      const int wq = t & 15, cq = (t >> 4) & 3, hg = t >> 6;
      float sreg[8];
      #pragma unroll
      for (int j = 0; j < 8; ++j) sreg[j] = sl[cq*8 + j];
      #pragma unroll
      for (int it = 0; it < 2; ++it) {
        const int h = h8*8 + it*4 + hg;
        float f[8][4];
        #pragma unroll
        for (int j = 0; j < 8; ++j) {
          const float* xp = (const float*)x + ((size_t)(((b*512) + ck*32 + cq*8 + j)*64 + h)*64 + wq*4);
          float4 v = *(const float4*)xp;
          f[j][0] = v.x; f[j][1] = v.y; f[j][2] = v.z; f[j][3] = v.w;
        }
        u16* xrow = xT + (size_t)(((b*16 + ck)*64 + h)*256)*8;
        #pragma unroll
        for (int wk = 0; wk < 4; ++wk) {
          u32 outp[4];
          #pragma unroll
          for (int i = 0; i < 4; ++i)
            outp[i] = (u32)f2bf(f[2*i][wk]*sreg[2*i]) | ((u32)f2bf(f[2*i+1][wk]*sreg[2*i+1]) << 16);
          uint4 po = {outp[0], outp[1], outp[2], outp[3]};
          *(uint4*)&xrow[(size_t)(cq*64 + wq*4 + wk)*8] = po;   // cell = q*64 + w (unchanged)
        }
      }
    }
  }
}

// ---------------- K2: MFMA conv (R9 verified form, 133-137us, replay-proven) ----------------
// Per ck: {barrier, STAGE_X via gl16, vmcnt(0), barrier, STAGE_W(ck+1) prefetch, 9 taps}.
// Block 512 thr / 8 waves = 64 co x 16 h x 64 w (0.375 ds_reads/MFMA). Grid 256 = 1/CU,
// XCD-chunked (b = bid&7). LDS: xs [dr18][q4][c67] 77184 B + wsm 2x36864 B = 150912 B.
__global__ __launch_bounds__(512, 2) void conv_kernel(const u16* __restrict__ xT, const u16* __restrict__ wT,
                                                      float* __restrict__ y, float* __restrict__ part) {
  __shared__ __align__(16) u16 xs[18*4*67*8];    // 77184 B
  __shared__ __align__(16) u16 wsm[2*2304*8];    // 73728 B
  const int tid = threadIdx.x;
  const int lane = tid & 63;
  const int wid = tid >> 6;            // 0..7
  const int bid = blockIdx.x;
  const int b = bid & 7, ctb = (bid >> 3) & 7, hb = bid >> 6;  // XCD-chunk: xcd = bid%8 = b
  const int ct0 = ctb * 64;
  const int h0 = hb * 16;
  const int m = lane & 15, qd = lane >> 4;

  // zero xs once: halo cells (c=0,65,66) + never-staged rows (dr=0 @hb=0, dr=17 @hb=3)
  {
    uint4 z = {0,0,0,0};
    for (int i = tid; i < 4824; i += 512) *(uint4*)&xs[i*8] = z;
  }

  floatx4 acc[4][8];
  #pragma unroll
  for (int i = 0; i < 4; ++i) {
    #pragma unroll
    for (int j = 0; j < 8; ++j) acc[i][j] = (floatx4)(0.f);
  }

  // stage x(ck): 72 lane-linear slices (18 dr x 4 q), 9 per wave
  #define STAGE_X(ckn)                                                                     \
    for (int sl = wid; sl < 72; sl += 8) {                                                 \
      int dr = sl >> 2, q = sl & 3;                                                        \
      int hin = h0 + dr - 1;                                                               \
      if (hin >= 0 && hin <= 63) {                                                         \
        const u16* src = xT + ((size_t)(((b*16 + (ckn))*64 + hin)*256 + q*64 + lane))*8;   \
        gl16(src, &xs[((dr*4 + q)*67 + 1)*8]);                                             \
      }                                                                                    \
    }
  // stage w(ck) into buffer bn: 36 lane-linear slices
  #define STAGE_W(ckn, bn)                                                                 \
    for (int j = wid; j < 36; j += 8) {                                                    \
      const u16* src = wT + ((size_t)(((ckn)*8 + ctb)*2304 + j*64 + lane))*8;              \
      gl16(src, &wsm[((bn)*2304 + j*64)*8]);                                               \
    }

  __syncthreads();             // zeros in LDS before any DMA lands around them
  STAGE_W(0, 0);               // wsm(0) prefetch; drained by first in-loop vmcnt

  for (int ck = 0; ck < 16; ++ck) {
    const int buf = ck & 1;
    __syncthreads();           // compute(ck-1) done: xs free, wsm[buf^1] free

    STAGE_X(ck);
    asm volatile("s_waitcnt vmcnt(0)" ::: "memory");  // xs(ck) + own wsm(ck) DMAs complete
    __syncthreads();           // all waves' stages visible

    if (ck < 15) STAGE_W(ck + 1, buf ^ 1);   // prefetch next weights under compute(ck)

    const u16* wb = &wsm[buf*2304*8];
    #pragma unroll
    for (int tap = 0; tap < 9; ++tap) {
      const int k1 = tap / 3, k2 = tap - k1*3;
      short8 af[4], bfr[8];
      #pragma unroll
      for (int mi = 0; mi < 4; ++mi)
        af[mi] = *(const short8*)&wb[((tap*4 + qd)*64 + mi*16 + m)*8];
      #pragma unroll
      for (int hh = 0; hh < 2; ++hh) {
        const int dr = wid*2 + hh + k1;       // 0..17
        #pragma unroll
        for (int nw = 0; nw < 4; ++nw)
          bfr[hh*4 + nw] = *(const short8*)&xs[((dr*4 + qd)*67 + nw*16 + m + k2)*8];
      }
      #pragma unroll
      for (int ni = 0; ni < 8; ++ni) {
        #pragma unroll
        for (int mi = 0; mi < 4; ++mi)
          acc[mi][ni] = __builtin_amdgcn_mfma_f32_16x16x32_bf16(af[mi], bfr[ni], acc[mi][ni], 0, 0, 0);
      }
    }
  }
  #undef STAGE_X
  #undef STAGE_W

  // write y (pre-norm conv result, f32) into d_out
  #pragma unroll
  for (int mi = 0; mi < 4; ++mi) {
    #pragma unroll
    for (int hh = 0; hh < 2; ++hh) {
      const int h = h0 + wid*2 + hh;
      #pragma unroll
      for (int nw = 0; nw < 4; ++nw) {
        #pragma unroll
        for (int r = 0; r < 4; ++r) {
          int co = ct0 + mi*16 + qd*4 + r;    // C/D: row=(lane>>4)*4+reg, col=lane&15
          int w = nw*16 + m;
          y[(size_t)(((b*512) + co)*64 + h)*64 + w] = acc[mi][hh*4 + nw][r];
        }
      }
    }
  }

  // fused IN partials: per-cout sum / sumsq over this block's 16x64 tile
  float s1[16], s2[16];
  #pragma unroll
  for (int mi = 0; mi < 4; ++mi) {
    #pragma unroll
    for (int r = 0; r < 4; ++r) {
      float a = 0.f, aa = 0.f;
      #pragma unroll
      for (int ni = 0; ni < 8; ++ni) {
        float v = acc[mi][ni][r];
        a += v; aa += v*v;
      }
      s1[mi*4+r] = a; s2[mi*4+r] = aa;
    }
  }
  #pragma unroll
  for (int off = 1; off < 16; off <<= 1) {
    #pragma unroll
    for (int i = 0; i < 16; ++i) {
      s1[i] += __shfl_xor(s1[i], off, 64);
      s2[i] += __shfl_xor(s2[i], off, 64);
    }
  }
  __syncthreads();                 // all waves done reading xs for MFMA
  float* red = (float*)xs;         // reuse LDS: [wid8][co64][2] = 1024 floats
  if (m == 0) {
    #pragma unroll
    for (int mi = 0; mi < 4; ++mi) {
      #pragma unroll
      for (int r = 0; r < 4; ++r) {
        int co = mi*16 + qd*4 + r;
        red[(wid*64 + co)*2 + 0] = s1[mi*4+r];
        red[(wid*64 + co)*2 + 1] = s2[mi*4+r];
      }
    }
  }
  __syncthreads();
  if (tid < 128) {
    int co = tid >> 1, which = tid & 1;
    float v = 0.f;
    #pragma unroll
    for (int w8 = 0; w8 < 8; ++w8) v += red[(w8*64 + co)*2 + which];
    part[(size_t)(((b*4 + hb)*512) + ct0 + co)*2 + which] = v;
  }
}

// ---------------- K3: finalize + normalize + CLADE (R9 exact, replay-proven) ----------------
__global__ __launch_bounds__(256) void epi_kernel(float* __restrict__ y, const float* __restrict__ part,
                                                  const float* __restrict__ s, const float* __restrict__ wsqT2,
                                                  const float* __restrict__ cw, const float* __restrict__ cb,
                                                  const int* __restrict__ label) {
  const int bc = blockIdx.x;           // 4096 = b*512+co
  const int b = bc >> 9, co = bc & 511;
  const int t = threadIdx.x;
  __shared__ float tabw[35], tabb[35];
  __shared__ float redp[4];
  __shared__ float2 msh;
  if (t < 35) { tabw[t] = cw[t*512 + co]; tabb[t] = cb[t*512 + co]; }

  // SS partial: thread t covers ci = t, t+256 (coalesced)
  const float* sb = s + b*512;
  const float* wq = wsqT2 + (size_t)co*512;
  float ep;
  {
    float s0 = sb[t], s1v = sb[t + 256];
    ep = s0*s0*wq[t] + s1v*s1v*wq[t + 256];
  }
  #pragma unroll
  for (int off = 1; off < 64; off <<= 1) ep += __shfl_xor(ep, off, 64);
  if ((t & 63) == 0) redp[t >> 6] = ep;
  __syncthreads();
  if (t == 0) {
    float SS = redp[0] + redp[1] + redp[2] + redp[3];
    float S = 0.f, Q = 0.f;
    const float2* pv = (const float2*)part;
    #pragma unroll
    for (int hb = 0; hb < 4; ++hb) {
      float2 p = pv[(size_t)((b*4 + hb)*512) + co];
      S += p.x; Q += p.y;
    }
    float mval = S * (1.f/4096.f);
    float var = fmaxf(Q * (1.f/4096.f) - mval*mval, 0.f);
    float eps = 1e-5f*SS + 4.608e-10f;   // = eps_in/(scale*demod)^2, exact
    msh = make_float2(mval, rsqrtf(var + eps));
  }
  __syncthreads();
  const float mval = msh.x, is = msh.y;

  float* yp = y + (size_t)bc*4096 + t*16;
  const int* lp = label + b*4096 + t*16;
  #pragma unroll
  for (int u = 0; u < 4; ++u) {
    float4 v = *(const float4*)(yp + u*4);
    int4 l = *(const int4*)(lp + u*4);
    float4 o;
    o.x = (v.x - mval)*is*tabw[l.x] + tabb[l.x];
    o.y = (v.y - mval)*is*tabw[l.y] + tabb[l.y];
    o.z = (v.z - mval)*is*tabw[l.z] + tabb[l.z];
    o.w = (v.w - mval)*is*tabw[l.w] + tabb[l.w];
    *(float4*)(yp + u*4) = o;
  }
}

extern "C" void kernel_launch(void* const* d_in, const int* in_sizes, int n_in,
                              void* d_out, int out_size, void* d_ws, size_t ws_size,
                              hipStream_t stream) {
  (void)in_sizes; (void)n_in; (void)out_size; (void)ws_size;
  const void* input       = d_in[0];
  const void* style       = d_in[1];
  const void* class_style = d_in[2];
  const void* weight      = d_in[3];
  const void* mod_w       = d_in[4];
  const void* mod_b       = d_in[5];
  const void* cw_w        = d_in[6];
  const void* cw_b        = d_in[7];
  const void* cb_w        = d_in[8];
  const void* cb_b        = d_in[9];
  const int* label        = (const int*)d_in[10];
  float* y = (float*)d_out;                   // f32 conv result in d_out, normalized in place

  char* ws = (char*)d_ws;
  u16*   xT    = (u16*)  (ws + 0);            // 33,554,432 B  [b][ck16][h][q4][w64] bf16 cells
  u16*   wT    = (u16*)  (ws + 33554432);     //  4,718,592 B  [ck16][ctb8][2304 cells] bf16
  float* wsqT2 = (float*)(ws + 38273024);     //  1,048,576 B  [cout][cin]
  float* s     = (float*)(ws + 39321600);     //     16,384 B  [b][ci]
  float* cw    = (float*)(ws + 39337984);     //     71,680 B  [ncls][cout]
  float* cb    = (float*)(ws + 39409664);     //     71,680 B
  float* part  = (float*)(ws + 39481344);     //    131,072 B  [b][hb4][cout][2]  (total 39,612,416 B)

  hipLaunchKernelGGL(prep_kernel, dim3(1614), dim3(256), 0, stream,
                     style, class_style, weight, mod_w, mod_b, cw_w, cw_b, cb_w, cb_b,
                     input, s, cw, cb, wT, wsqT2, xT);
  hipLaunchKernelGGL(conv_kernel, dim3(256), dim3(512), 0, stream, xT, wT, y, part);
  hipLaunchKernelGGL(epi_kernel, dim3(4096), dim3(256), 0, stream, y, part, s, wsqT2, cw, cb, label);
}

// Round 15
// 300.303 us; speedup vs baseline: 1.0785x; 1.0225x over previous
//
#include <hip/hip_runtime.h>

typedef unsigned short u16;
typedef unsigned int u32;
typedef __attribute__((ext_vector_type(8))) short short8;
typedef __attribute__((ext_vector_type(4))) float floatx4;

typedef const u32 __attribute__((address_space(1))) glb_u32;
typedef u32 __attribute__((address_space(3))) lds_u32;

__device__ inline float bf2f(u16 h) {
  union { u32 u; float f; } v; v.u = ((u32)h) << 16; return v.f;
}
__device__ inline u16 f2bf(float f) {
  union { float f; u32 u; } v; v.f = f;
  u32 u = v.u;
  return (u16)((u + 0x7fffu + ((u >> 16) & 1u)) >> 16);
}
// dtype-generic load: isbf is wave-uniform (from per-block sniffer)
__device__ inline float ldf(const void* p, int i, int isbf) {
  return isbf ? bf2f(((const u16*)p)[i]) : ((const float*)p)[i];
}
// async global->LDS DMA: 16B/lane, dest = wave-uniform base + lane*16, src per-lane
__device__ inline void gl16(const void* g, void* l) {
  __builtin_amdgcn_global_load_lds((glb_u32*)g, (lds_u32*)l, 16, 0, 0);
}

// ---------------- K1: fused prep (R14 verified) ----------------
// One kernel, 1614 blocks, three roles (block-uniform branch):
//   [0,78)      styles rows  -> s[8][512], cw[35][512], cb[35][512]
//   [78,590)    wprep        -> wT[ck][ctblk][(tap*4+q)*64+co] cells, wsqT2[co][ci]
//   [590,1614)  xtrans       -> xT[b][ck][h][q][w] bf16 cells; block per (b,ck,h8).
// All isbf loads vectorized to short8 (16B) — G13.
__global__ __launch_bounds__(256) void prep_kernel(
    const void* __restrict__ style, const void* __restrict__ class_style,
    const void* __restrict__ weight,
    const void* __restrict__ mod_w, const void* __restrict__ mod_b,
    const void* __restrict__ cw_w, const void* __restrict__ cw_b,
    const void* __restrict__ cb_w, const void* __restrict__ cb_b,
    const void* __restrict__ x,
    float* __restrict__ s, float* __restrict__ cw, float* __restrict__ cb,
    u16* __restrict__ wT, float* __restrict__ wsqT2, u16* __restrict__ xT) {
  __shared__ float smem[4608];       // union: styles v[512] | wprep wsmem[4608] | xtrans sv[512]+pr[256]+sl[32]
  __shared__ int cnt;
  const int t = threadIdx.x;

  if (t == 0) cnt = 0;
  __syncthreads();
  {
    u32 v = ((const u32*)weight)[1024 + t];
    int e = (v >> 7) & 0xFF;
    if (e >= 96 && e <= 160) atomicAdd(&cnt, 1);
  }
  __syncthreads();
  const int isbf = (cnt >= 154) ? 1 : 0;
  const int bid = blockIdx.x;

  if (bid < 78) {
    // ---- styles role ----
    int row = bid;
    const void *vec, *wm, *bias; float* out; int voff;
    if (row < 8)        { vec = style;       voff = row*512;      wm = mod_w; bias = mod_b; out = s  + row*512; }
    else if (row < 43)  { vec = class_style; voff = (row-8)*512;  wm = cw_w;  bias = cw_b;  out = cw + (row-8)*512; }
    else                { vec = class_style; voff = (row-43)*512; wm = cb_w;  bias = cb_b;  out = cb + (row-43)*512; }
    float* v = smem;
    for (int i = t; i < 512; i += 256) v[i] = ldf(vec, voff + i, isbf);
    __syncthreads();
    const float inv = 0.04419417382415922f;  // 1/sqrt(512)
    for (int o = t; o < 512; o += 256) {
      float acc = 0.f;
      if (isbf) {
        const short8* wr8 = (const short8*)((const u16*)wm + (size_t)o*512);  // 16B-aligned
        for (int k = 0; k < 64; ++k) {
          short8 p = wr8[k];
          #pragma unroll
          for (int e = 0; e < 8; ++e) acc += bf2f((u16)p[e]) * v[k*8 + e];
        }
      } else {
        const float4* wr = (const float4*)((const float*)wm + o*512);
        for (int k = 0; k < 128; ++k) {
          float4 p = wr[k];
          acc += p.x*v[k*4+0] + p.y*v[k*4+1] + p.z*v[k*4+2] + p.w*v[k*4+3];
        }
      }
      out[o] = acc * inv + ldf(bias, o, isbf);
    }
  } else if (bid < 590) {
    // ---- wprep role ----
    const int co = bid - 78;
    const int ctb = co >> 6, col = co & 63;
    float* wsmem = smem;
    if (isbf) {
      const short8* wp = (const short8*)((const u16*)weight + (size_t)co*4608);  // 9216B: 16B-aligned
      for (int i = t; i < 576; i += 256) {
        short8 v = wp[i];
        #pragma unroll
        for (int e = 0; e < 8; ++e) wsmem[i*8 + e] = bf2f((u16)v[e]);
      }
    } else {
      for (int i = t; i < 4608; i += 256)
        wsmem[i] = ((const float*)weight)[co*4608 + i];   // coalesced
    }
    __syncthreads();
    for (int ci = t; ci < 512; ci += 256) {
      float sq = 0.f;
      const int ck = ci >> 5, q = (ci >> 3) & 3, e = ci & 7;
      #pragma unroll
      for (int tap = 0; tap < 9; ++tap) {
        float fv = wsmem[ci*9 + tap];
        sq += fv*fv;
        wT[((size_t)(ck*8 + ctb)*2304 + (tap*4 + q)*64 + col)*8 + e] = f2bf(fv);
      }
      wsqT2[(size_t)co*512 + ci] = sq;             // coalesced store
    }
  } else {
    // ---- xtrans role: block per (b, ck, h8); s once per 8 h rows; vectorized IO ----
    const int r = bid - 590;
    const int h8 = r & 7, ck = (r >> 3) & 15, b = r >> 7;
    float* sv = smem;          // style vector [512]
    float* pr = smem + 512;    // partials [32 rows][8 segs]
    float* sl = smem + 768;    // s_local [32]
    for (int i = t; i < 512; i += 256) sv[i] = ldf(style, b*512 + i, isbf);
    __syncthreads();
    const float inv = 0.04419417382415922f;
    {
      const int row = t >> 3, seg = t & 7;
      const int ci = ck*32 + row;
      const float* svp = sv + seg*64;
      float partial = 0.f;
      if (isbf) {
        const short8* wr8 = (const short8*)((const u16*)mod_w + (size_t)ci*512 + seg*64);  // 128B-aligned
        #pragma unroll
        for (int k8 = 0; k8 < 8; ++k8) {
          short8 p = wr8[k8];
          #pragma unroll
          for (int e = 0; e < 8; ++e) partial += bf2f((u16)p[e]) * svp[k8*8 + e];
        }
      } else {
        const float4* wr = (const float4*)((const float*)mod_w + (size_t)ci*512 + seg*64);
        #pragma unroll
        for (int k = 0; k < 16; ++k) {
          float4 p = wr[k];
          partial += p.x*svp[k*4+0] + p.y*svp[k*4+1] + p.z*svp[k*4+2] + p.w*svp[k*4+3];
        }
      }
      pr[t] = partial;
    }
    __syncthreads();
    if (t < 32) {
      float a = 0.f;
      #pragma unroll
      for (int g = 0; g < 8; ++g) a += pr[t*8 + g];
      sl[t] = a * inv + ldf(mod_b, ck*32 + t, isbf);
    }
    __syncthreads();
    if (isbf) {
      // thread = (w8 8, cq 4, hg 8): 8 w-columns x 8 ci at h = h8*8 + hg; 16B loads,
      // 128B-contiguous stores/thread. Cell bijection: cell cq*64 + w8*8 + wk, slot j = ci j.
      const int w8 = t & 7, cq = (t >> 3) & 3, hg = t >> 5;
      const int h = h8*8 + hg;
      float sreg[8];
      #pragma unroll
      for (int j = 0; j < 8; ++j) sreg[j] = sl[cq*8 + j];
      u16 fb[8][8];
      #pragma unroll
      for (int j = 0; j < 8; ++j) {
        const u16* xp = (const u16*)x + ((size_t)(((b*512) + ck*32 + cq*8 + j)*64 + h)*64 + w8*8);
        short8 v = *(const short8*)xp;     // 16B-aligned
        #pragma unroll
        for (int wk = 0; wk < 8; ++wk) fb[j][wk] = f2bf(bf2f((u16)v[wk]) * sreg[j]);
      }
      u16* xrow = xT + (size_t)(((b*16 + ck)*64 + h)*256)*8;
      #pragma unroll
      for (int wk = 0; wk < 8; ++wk) {
        u32 outp[4];
        #pragma unroll
        for (int i = 0; i < 4; ++i)
          outp[i] = (u32)fb[2*i][wk] | ((u32)fb[2*i+1][wk] << 16);
        uint4 po = {outp[0], outp[1], outp[2], outp[3]};
        *(uint4*)&xrow[(size_t)(cq*64 + w8*8 + wk)*8] = po;
      }
    } else {
      // f32 path: float4 x-reads along w, 64B contiguous stores
      const int wq = t & 15, cq = (t >> 4) & 3, hg = t >> 6;
      float sreg[8];
      #pragma unroll
      for (int j = 0; j < 8; ++j) sreg[j] = sl[cq*8 + j];
      #pragma unroll
      for (int it = 0; it < 2; ++it) {
        const int h = h8*8 + it*4 + hg;
        float f[8][4];
        #pragma unroll
        for (int j = 0; j < 8; ++j) {
          const float* xp = (const float*)x + ((size_t)(((b*512) + ck*32 + cq*8 + j)*64 + h)*64 + wq*4);
          float4 v = *(const float4*)xp;
          f[j][0] = v.x; f[j][1] = v.y; f[j][2] = v.z; f[j][3] = v.w;
        }
        u16* xrow = xT + (size_t)(((b*16 + ck)*64 + h)*256)*8;
        #pragma unroll
        for (int wk = 0; wk < 4; ++wk) {
          u32 outp[4];
          #pragma unroll
          for (int i = 0; i < 4; ++i)
            outp[i] = (u32)f2bf(f[2*i][wk]*sreg[2*i]) | ((u32)f2bf(f[2*i+1][wk]*sreg[2*i+1]) << 16);
          uint4 po = {outp[0], outp[1], outp[2], outp[3]};
          *(uint4*)&xrow[(size_t)(cq*64 + wq*4 + wk)*8] = po;   // cell = q*64 + w (unchanged)
        }
      }
    }
  }
}

// ---------------- K2: MFMA conv (R9 core, replay-proven) + bf16-intermediate option ----------------
// YBF=1: write pre-norm conv result as bf16 into workspace ybf (33.5 MB) instead of f32
// into d_out — halves conv write traffic and epi read traffic (67 MB HBM total saved).
// IN statistics (part) are computed from f32 acc BEFORE rounding (unchanged), so mu/istd
// precision is unaffected; only the normalized value carries the ~2^-9 bf16 rounding
// (error ~0.01-0.06 << 0.4325 threshold). YBF=0 path is byte-equivalent to R14.
template<int YBF>
__global__ __launch_bounds__(512, 2) void conv_t(const u16* __restrict__ xT, const u16* __restrict__ wT,
                                                 float* __restrict__ y, u16* __restrict__ ybf,
                                                 float* __restrict__ part) {
  __shared__ __align__(16) u16 xs[18*4*67*8];    // 77184 B
  __shared__ __align__(16) u16 wsm[2*2304*8];    // 73728 B
  const int tid = threadIdx.x;
  const int lane = tid & 63;
  const int wid = tid >> 6;            // 0..7
  const int bid = blockIdx.x;
  const int b = bid & 7, ctb = (bid >> 3) & 7, hb = bid >> 6;  // XCD-chunk: xcd = bid%8 = b
  const int ct0 = ctb * 64;
  const int h0 = hb * 16;
  const int m = lane & 15, qd = lane >> 4;

  // zero xs once: halo cells (c=0,65,66) + never-staged rows (dr=0 @hb=0, dr=17 @hb=3)
  {
    uint4 z = {0,0,0,0};
    for (int i = tid; i < 4824; i += 512) *(uint4*)&xs[i*8] = z;
  }

  floatx4 acc[4][8];
  #pragma unroll
  for (int i = 0; i < 4; ++i) {
    #pragma unroll
    for (int j = 0; j < 8; ++j) acc[i][j] = (floatx4)(0.f);
  }

  // stage x(ck): 72 lane-linear slices (18 dr x 4 q), 9 per wave
  #define STAGE_X(ckn)                                                                     \
    for (int sl = wid; sl < 72; sl += 8) {                                                 \
      int dr = sl >> 2, q = sl & 3;                                                        \
      int hin = h0 + dr - 1;                                                               \
      if (hin >= 0 && hin <= 63) {                                                         \
        const u16* src = xT + ((size_t)(((b*16 + (ckn))*64 + hin)*256 + q*64 + lane))*8;   \
        gl16(src, &xs[((dr*4 + q)*67 + 1)*8]);                                             \
      }                                                                                    \
    }
  // stage w(ck) into buffer bn: 36 lane-linear slices
  #define STAGE_W(ckn, bn)                                                                 \
    for (int j = wid; j < 36; j += 8) {                                                    \
      const u16* src = wT + ((size_t)(((ckn)*8 + ctb)*2304 + j*64 + lane))*8;              \
      gl16(src, &wsm[((bn)*2304 + j*64)*8]);                                               \
    }

  __syncthreads();             // zeros in LDS before any DMA lands around them
  STAGE_W(0, 0);               // wsm(0) prefetch; drained by first in-loop vmcnt

  for (int ck = 0; ck < 16; ++ck) {
    const int buf = ck & 1;
    __syncthreads();           // compute(ck-1) done: xs free, wsm[buf^1] free

    STAGE_X(ck);
    asm volatile("s_waitcnt vmcnt(0)" ::: "memory");  // xs(ck) + own wsm(ck) DMAs complete
    __syncthreads();           // all waves' stages visible

    if (ck < 15) STAGE_W(ck + 1, buf ^ 1);   // prefetch next weights under compute(ck)

    const u16* wb = &wsm[buf*2304*8];
    #pragma unroll
    for (int tap = 0; tap < 9; ++tap) {
      const int k1 = tap / 3, k2 = tap - k1*3;
      short8 af[4], bfr[8];
      #pragma unroll
      for (int mi = 0; mi < 4; ++mi)
        af[mi] = *(const short8*)&wb[((tap*4 + qd)*64 + mi*16 + m)*8];
      #pragma unroll
      for (int hh = 0; hh < 2; ++hh) {
        const int dr = wid*2 + hh + k1;       // 0..17
        #pragma unroll
        for (int nw = 0; nw < 4; ++nw)
          bfr[hh*4 + nw] = *(const short8*)&xs[((dr*4 + qd)*67 + nw*16 + m + k2)*8];
      }
      #pragma unroll
      for (int ni = 0; ni < 8; ++ni) {
        #pragma unroll
        for (int mi = 0; mi < 4; ++mi)
          acc[mi][ni] = __builtin_amdgcn_mfma_f32_16x16x32_bf16(af[mi], bfr[ni], acc[mi][ni], 0, 0, 0);
      }
    }
  }
  #undef STAGE_X
  #undef STAGE_W

  // write pre-norm conv result: bf16 -> ybf (YBF=1) or f32 -> y (YBF=0)
  #pragma unroll
  for (int mi = 0; mi < 4; ++mi) {
    #pragma unroll
    for (int hh = 0; hh < 2; ++hh) {
      const int h = h0 + wid*2 + hh;
      #pragma unroll
      for (int nw = 0; nw < 4; ++nw) {
        #pragma unroll
        for (int r = 0; r < 4; ++r) {
          int co = ct0 + mi*16 + qd*4 + r;    // C/D: row=(lane>>4)*4+reg, col=lane&15
          int w = nw*16 + m;
          size_t idx = (size_t)(((b*512) + co)*64 + h)*64 + w;
          if constexpr (YBF) ybf[idx] = f2bf(acc[mi][hh*4 + nw][r]);
          else               y[idx]   = acc[mi][hh*4 + nw][r];
        }
      }
    }
  }

  // fused IN partials: per-cout sum / sumsq over this block's 16x64 tile (f32 acc, pre-round)
  float s1[16], s2[16];
  #pragma unroll
  for (int mi = 0; mi < 4; ++mi) {
    #pragma unroll
    for (int r = 0; r < 4; ++r) {
      float a = 0.f, aa = 0.f;
      #pragma unroll
      for (int ni = 0; ni < 8; ++ni) {
        float v = acc[mi][ni][r];
        a += v; aa += v*v;
      }
      s1[mi*4+r] = a; s2[mi*4+r] = aa;
    }
  }
  #pragma unroll
  for (int off = 1; off < 16; off <<= 1) {
    #pragma unroll
    for (int i = 0; i < 16; ++i) {
      s1[i] += __shfl_xor(s1[i], off, 64);
      s2[i] += __shfl_xor(s2[i], off, 64);
    }
  }
  __syncthreads();                 // all waves done reading xs for MFMA
  float* red = (float*)xs;         // reuse LDS: [wid8][co64][2] = 1024 floats
  if (m == 0) {
    #pragma unroll
    for (int mi = 0; mi < 4; ++mi) {
      #pragma unroll
      for (int r = 0; r < 4; ++r) {
        int co = mi*16 + qd*4 + r;
        red[(wid*64 + co)*2 + 0] = s1[mi*4+r];
        red[(wid*64 + co)*2 + 1] = s2[mi*4+r];
      }
    }
  }
  __syncthreads();
  if (tid < 128) {
    int co = tid >> 1, which = tid & 1;
    float v = 0.f;
    #pragma unroll
    for (int w8 = 0; w8 < 8; ++w8) v += red[(w8*64 + co)*2 + which];
    part[(size_t)(((b*4 + hb)*512) + ct0 + co)*2 + which] = v;
  }
}

// ---------------- K3: finalize + normalize + CLADE (R9 stats; bf16-read option) ----------------
template<int YBF>
__global__ __launch_bounds__(256) void epi_t(float* __restrict__ y, const u16* __restrict__ ybf,
                                             const float* __restrict__ part,
                                             const float* __restrict__ s, const float* __restrict__ wsqT2,
                                             const float* __restrict__ cw, const float* __restrict__ cb,
                                             const int* __restrict__ label) {
  const int bc = blockIdx.x;           // 4096 = b*512+co
  const int b = bc >> 9, co = bc & 511;
  const int t = threadIdx.x;
  __shared__ float tabw[35], tabb[35];
  __shared__ float redp[4];
  __shared__ float2 msh;
  if (t < 35) { tabw[t] = cw[t*512 + co]; tabb[t] = cb[t*512 + co]; }

  // SS partial: thread t covers ci = t, t+256 (coalesced)
  const float* sb = s + b*512;
  const float* wq = wsqT2 + (size_t)co*512;
  float ep;
  {
    float s0 = sb[t], s1v = sb[t + 256];
    ep = s0*s0*wq[t] + s1v*s1v*wq[t + 256];
  }
  #pragma unroll
  for (int off = 1; off < 64; off <<= 1) ep += __shfl_xor(ep, off, 64);
  if ((t & 63) == 0) redp[t >> 6] = ep;
  __syncthreads();
  if (t == 0) {
    float SS = redp[0] + redp[1] + redp[2] + redp[3];
    float S = 0.f, Q = 0.f;
    const float2* pv = (const float2*)part;
    #pragma unroll
    for (int hb = 0; hb < 4; ++hb) {
      float2 p = pv[(size_t)((b*4 + hb)*512) + co];
      S += p.x; Q += p.y;
    }
    float mval = S * (1.f/4096.f);
    float var = fmaxf(Q * (1.f/4096.f) - mval*mval, 0.f);
    float eps = 1e-5f*SS + 4.608e-10f;   // = eps_in/(scale*demod)^2, exact
    msh = make_float2(mval, rsqrtf(var + eps));
  }
  __syncthreads();
  const float mval = msh.x, is = msh.y;

  float* yp = y + (size_t)bc*4096 + t*16;
  const int* lp = label + b*4096 + t*16;
  float vin[16];
  if constexpr (YBF) {
    const u16* bp = ybf + (size_t)bc*4096 + t*16;
    short8 v0 = *(const short8*)bp;          // 16B
    short8 v1 = *(const short8*)(bp + 8);
    #pragma unroll
    for (int e = 0; e < 8; ++e) { vin[e] = bf2f((u16)v0[e]); vin[8+e] = bf2f((u16)v1[e]); }
  } else {
    #pragma unroll
    for (int u = 0; u < 4; ++u) {
      float4 v = *(const float4*)(yp + u*4);
      vin[u*4+0] = v.x; vin[u*4+1] = v.y; vin[u*4+2] = v.z; vin[u*4+3] = v.w;
    }
  }
  #pragma unroll
  for (int u = 0; u < 4; ++u) {
    int4 l = *(const int4*)(lp + u*4);
    float4 o;
    o.x = (vin[u*4+0] - mval)*is*tabw[l.x] + tabb[l.x];
    o.y = (vin[u*4+1] - mval)*is*tabw[l.y] + tabb[l.y];
    o.z = (vin[u*4+2] - mval)*is*tabw[l.z] + tabb[l.z];
    o.w = (vin[u*4+3] - mval)*is*tabw[l.w] + tabb[l.w];
    *(float4*)(yp + u*4) = o;
  }
}

extern "C" void kernel_launch(void* const* d_in, const int* in_sizes, int n_in,
                              void* d_out, int out_size, void* d_ws, size_t ws_size,
                              hipStream_t stream) {
  (void)in_sizes; (void)n_in; (void)out_size;
  const void* input       = d_in[0];
  const void* style       = d_in[1];
  const void* class_style = d_in[2];
  const void* weight      = d_in[3];
  const void* mod_w       = d_in[4];
  const void* mod_b       = d_in[5];
  const void* cw_w        = d_in[6];
  const void* cw_b        = d_in[7];
  const void* cb_w        = d_in[8];
  const void* cb_b        = d_in[9];
  const int* label        = (const int*)d_in[10];
  float* y = (float*)d_out;                   // final f32 output (epi writes in place)

  char* ws = (char*)d_ws;
  u16*   xT    = (u16*)  (ws + 0);            // 33,554,432 B  [b][ck16][h][q4][w64] bf16 cells
  u16*   wT    = (u16*)  (ws + 33554432);     //  4,718,592 B  [ck16][ctb8][2304 cells] bf16
  float* wsqT2 = (float*)(ws + 38273024);     //  1,048,576 B  [cout][cin]
  float* s     = (float*)(ws + 39321600);     //     16,384 B  [b][ci]
  float* cw    = (float*)(ws + 39337984);     //     71,680 B  [ncls][cout]
  float* cb    = (float*)(ws + 39409664);     //     71,680 B
  float* part  = (float*)(ws + 39481344);     //    131,072 B  [b][hb4][cout][2]
  u16*   ybf   = (u16*)  (ws + 39612416);     // 33,554,432 B  bf16 pre-norm intermediate
  const size_t WS_NEED_BF = 39612416ull + 33554432ull;   // 73,166,848 B

  hipLaunchKernelGGL(prep_kernel, dim3(1614), dim3(256), 0, stream,
                     style, class_style, weight, mod_w, mod_b, cw_w, cw_b, cb_w, cb_b,
                     input, s, cw, cb, wT, wsqT2, xT);

  if (ws_size >= WS_NEED_BF) {
    hipLaunchKernelGGL((conv_t<1>), dim3(256), dim3(512), 0, stream, xT, wT, y, ybf, part);
    hipLaunchKernelGGL((epi_t<1>), dim3(4096), dim3(256), 0, stream, y, ybf, part, s, wsqT2, cw, cb, label);
  } else {
    hipLaunchKernelGGL((conv_t<0>), dim3(256), dim3(512), 0, stream, xT, wT, y, ybf, part);
    hipLaunchKernelGGL((epi_t<0>), dim3(4096), dim3(256), 0, stream, y, ybf, part, s, wsqT2, cw, cb, label);
  }
}